// Round 3
// baseline (2775.942 us; speedup 1.0000x reference)
//
#include <hip/hip_runtime.h>
#include <hip/hip_bf16.h>

// ---------------- constants ----------------
#define NB   4
#define DIM  128
#define KC   64
#define HH   48
#define WW   900
#define WPAD 1100
#define WST  1160   // guarded stride for conv-phase buffers: col = w + 2, zeros outside [0,1100)
#define NT   30
#define OC1  256
#define OC2  512
#define OC3  1024

typedef __attribute__((ext_vector_type(8))) short bf16x8;
typedef __attribute__((ext_vector_type(4))) float f32x4;
typedef unsigned short u16;
typedef unsigned int u32;

__device__ __forceinline__ u16 f2bf(float f){
  __hip_bfloat16 h = __float2bfloat16(f);
  u16 u; __builtin_memcpy(&u, &h, 2); return u;
}
__device__ __forceinline__ float bf2f(u16 u){
  __hip_bfloat16 h; __builtin_memcpy(&h, &u, 2); return __bfloat162float(h);
}

typedef __attribute__((address_space(1))) const u32 g_u32;
typedef __attribute__((address_space(3))) u32 l_u32;
// async global->LDS, 16B per lane; LDS dest = uniform base + lane*16
__device__ __forceinline__ void gll16(const void* g, void* l){
  __builtin_amdgcn_global_load_lds((g_u32*)g, (l_u32*)l, 16, 0, 0);
}

// ---------------- VLAD branch (fp32) ----------------

__global__ __launch_bounds__(256) void transpose_xt(const float* __restrict__ x, float* __restrict__ xt){
  __shared__ float tile[32][33];
  int n = blockIdx.z;
  int r0 = blockIdx.y*32, w0 = blockIdx.x*32;
  int t = threadIdx.x;
  int tr = t >> 5, tc = t & 31;
  #pragma unroll
  for (int i = 0; i < 4; ++i){
    int r = r0 + tr + i*8, w = w0 + tc;
    tile[tr + i*8][tc] = (w < WW) ? x[((size_t)n*(DIM*HH) + r)*WW + w] : 0.f;
  }
  __syncthreads();
  #pragma unroll
  for (int i = 0; i < 4; ++i){
    int w = w0 + tr + i*8, r = r0 + tc;
    if (w < WW) xt[((size_t)n*WW + w)*(DIM*HH) + r] = tile[tc][tr + i*8];
  }
}

__global__ __launch_bounds__(256) void vlad_softmax(const float* __restrict__ x,
    const float* __restrict__ conv_w, const float* __restrict__ conv_b, float* __restrict__ a){
  __shared__ float cwT[DIM*KC];
  __shared__ float cbs[KC];
  int t = threadIdx.x;
  for (int i = t; i < DIM*KC; i += 256){ int c = i >> 6, k = i & 63; cwT[i] = conv_w[k*DIM + c]; }
  if (t < KC) cbs[t] = conv_b[t];
  __syncthreads();
  int w = blockIdx.x*256 + t, h = blockIdx.y, n = blockIdx.z;
  bool ok = (w < WW);
  float lg[KC];
  #pragma unroll
  for (int k = 0; k < KC; ++k) lg[k] = cbs[k];
  const float* xp = x + (size_t)n*DIM*HH*WW + (size_t)h*WW + (ok ? w : 0);
  for (int c = 0; c < DIM; ++c){
    float xv = ok ? xp[(size_t)c*HH*WW] : 0.f;
    const float* cw = &cwT[c*KC];
    #pragma unroll
    for (int k = 0; k < KC; ++k) lg[k] += xv * cw[k];
  }
  float m = lg[0];
  #pragma unroll
  for (int k = 1; k < KC; ++k) m = fmaxf(m, lg[k]);
  float s = 0.f;
  #pragma unroll
  for (int k = 0; k < KC; ++k){ lg[k] = __expf(lg[k]-m); s += lg[k]; }
  float inv = 1.f/s;
  if (ok){
    float* dst = a + (((size_t)(n*HH + h))*WW + w)*KC;
    #pragma unroll
    for (int k = 0; k < KC; k += 4){
      float4 v = make_float4(lg[k]*inv, lg[k+1]*inv, lg[k+2]*inv, lg[k+3]*inv);
      *(float4*)&dst[k] = v;
    }
  }
}

// per (n,w): ya[k][c] = sum_h a[k,h]*x[c,h] - centers[k][c]*sum_h a[k,h]
__global__ __launch_bounds__(256) void vlad_xa(const float* __restrict__ xt, const float* __restrict__ a,
    const float* __restrict__ centers, float* __restrict__ ya){
  __shared__ float aT[HH][KC];
  __shared__ float xT[DIM*HH];
  int t = threadIdx.x, w = blockIdx.x, n = blockIdx.y;
  for (int i = t; i < HH*KC; i += 256){
    int h = i >> 6, k = i & 63;
    aT[h][k] = a[(((size_t)(n*HH + h))*WW + w)*KC + k];
  }
  {
    const float4* src = (const float4*)(xt + ((size_t)n*WW + w)*(DIM*HH));
    float4* dst4 = (float4*)xT;
    for (int i = t; i < (DIM*HH)/4; i += 256) dst4[i] = src[i];
  }
  __syncthreads();
  int k = t >> 2, cb4 = t & 3;
  float areg[HH];
  #pragma unroll
  for (int h = 0; h < HH; ++h) areg[h] = aT[h][k];
  float S = 0.f;
  #pragma unroll
  for (int h = 0; h < HH; ++h) S += areg[h];
  const float* ck = centers + (size_t)k*DIM;
  float* dst = ya + (((size_t)n*WW + w)*KC + k)*DIM;
  #pragma unroll 2
  for (int j = 0; j < 32; ++j){
    const float4* xr = (const float4*)&xT[(cb4 + 4*j)*HH];
    float s = 0.f;
    #pragma unroll
    for (int h4 = 0; h4 < HH/4; ++h4){
      float4 xv = xr[h4];
      s += areg[h4*4+0]*xv.x + areg[h4*4+1]*xv.y + areg[h4*4+2]*xv.z + areg[h4*4+3]*xv.w;
    }
    int c = cb4 + 4*j;
    dst[c] = s - ck[c]*S;
  }
}

// cumsum scan over padded w-order; emit boundary partials.
// cs layout: [n][k][slot][c], slot = t (window start, t=0..29) and 32+t (start+200)
__global__ __launch_bounds__(128) void vlad_scan(const float* __restrict__ ya, float* __restrict__ cs){
  int c = threadIdx.x, k = blockIdx.x, n = blockIdx.y;
  const float* base = ya + ((size_t)n*WW*KC + k)*DIM + c;
  float* csb = cs + ((size_t)(n*KC + k))*64*128 + c;
  float acc = 0.f;
  for (int p = 0; p < 1100; ++p){
    int w = (p < 100) ? p + 800 : ((p < 1000) ? p - 100 : p - 1000);
    int r30 = p % 30;
    if (r30 == 0 && p <= 870) csb[(p/30)*128] = acc;
    if (r30 == 20 && p >= 200 && p <= 1070) csb[(32 + (p-200)/30)*128] = acc;
    acc += base[(size_t)w*KC*DIM];
  }
}

// window value from cumsum diff + intra (per-cluster) L2 norm
__global__ __launch_bounds__(128) void vlad_win2(const float* __restrict__ cs, float* __restrict__ vlad){
  int c = threadIdx.x, k = blockIdx.x, tt = blockIdx.y, n = blockIdx.z;
  const float* base = cs + ((size_t)(n*KC + k))*64*128;
  float v = base[(32+tt)*128 + c] - base[tt*128 + c];
  float ss = v*v;
  #pragma unroll
  for (int m = 1; m < 64; m <<= 1) ss += __shfl_xor(ss, m);
  __shared__ float red[2];
  if ((c & 63) == 0) red[c >> 6] = ss;
  __syncthreads();
  float tot = red[0] + red[1];
  float inv = 1.f / fmaxf(sqrtf(tot), 1e-12f);
  vlad[(((size_t)(n*NT + tt))*KC + k)*DIM + c] = v*inv;
}

__global__ __launch_bounds__(256) void vlad_gnorm(float* __restrict__ vlad){
  int row = blockIdx.x, t = threadIdx.x;
  float4* v = (float4*)(vlad + (size_t)row*(KC*DIM));
  float4 r[8]; float ss = 0.f;
  #pragma unroll
  for (int i = 0; i < 8; ++i){
    r[i] = v[t + i*256];
    ss += r[i].x*r[i].x + r[i].y*r[i].y + r[i].z*r[i].z + r[i].w*r[i].w;
  }
  #pragma unroll
  for (int m = 1; m < 64; m <<= 1) ss += __shfl_xor(ss, m);
  __shared__ float red[4];
  if ((t & 63) == 0) red[t >> 6] = ss;
  __syncthreads();
  float tot = red[0]+red[1]+red[2]+red[3];
  float inv = 1.f / fmaxf(sqrtf(tot), 1e-12f);
  #pragma unroll
  for (int i = 0; i < 8; ++i){
    float4 o = r[i]; o.x*=inv; o.y*=inv; o.z*=inv; o.w*=inv;
    v[t + i*256] = o;
  }
}

// ---------------- conv tower (bf16 MFMA, NHWC, guarded stride WST) ----------------

__global__ __launch_bounds__(256) void build_xpb(const float* __restrict__ x, u16* __restrict__ xpb){
  __shared__ u16 tile[DIM][33];
  int t = threadIdx.x, h = blockIdx.y, n = blockIdx.z;
  int b0 = blockIdx.x*32;
  #pragma unroll
  for (int i = 0; i < 16; ++i){
    int e = t + i*256;
    int c = e >> 5, bl = e & 31;
    int b = b0 + bl, w = b - 2;
    float v = 0.f;
    if (w >= 0 && w < WPAD){
      int wsrc = (w + 800) % 900;
      v = x[((size_t)(n*DIM + c)*HH + h)*WW + wsrc];
    }
    tile[c][bl] = f2bf(v);
  }
  __syncthreads();
  #pragma unroll
  for (int i = 0; i < 16; ++i){
    int e = t + i*256;
    int bl = e >> 7, c = e & 127;
    int b = b0 + bl;
    if (b < WST) xpb[((size_t)(n*HH + h)*WST + b)*DIM + c] = tile[c][bl];
  }
}

__global__ __launch_bounds__(256) void pack_w(const float* __restrict__ w, u16* __restrict__ wp, int OC, int IC){
  int idx = blockIdx.x*256 + threadIdx.x;
  int total = OC*IC*25;
  if (idx >= total) return;
  int ic = idx % IC; int r = idx / IC; int oc = r % OC; int tap = r / OC;
  wp[idx] = f2bf(w[((size_t)oc*IC + ic)*25 + tap]);
}

// 5x5 conv pad 2, NHWC bf16, guarded input. Block 128oc x 128w, 4 waves of 64x64.
// Counted-vmcnt software pipeline: double-buffered sW (per-tap) and sIn (per (dh,icb) slab).
// Per phase: issue next sW prefetch (8 gll16/wave); at dw==3 also next sIn (9/wave);
// then s_waitcnt vmcnt(8|17), s_barrier, MFMA, s_barrier. Never vmcnt(0) in loop.
template<int IC, int OC, int H>
__global__ __launch_bounds__(256,1) void conv5x5(const u16* __restrict__ in, const u16* __restrict__ wp,
    const float* __restrict__ bias, u16* __restrict__ out){
  constexpr int NICB = IC/128;
  constexpr int LN = (NICB==1?0:(NICB==2?1:2));
  __shared__ u16 sW[2][128*128];    // 2 x 32 KB
  __shared__ u16 sIn[2][144*128];   // 2 x 36 KB (rows 132..143 junk, clamped src)
  int t = threadIdx.x;
  int wave = t >> 6, lane = t & 63, lr = lane & 15, lgp = lane >> 4;
  int w0  = blockIdx.x * 128;
  int ocb = blockIdx.y * 128;
  int nh = blockIdx.z; int n = nh / H, h = nh % H;
  int wo_oc = (wave & 1)*64, wo_w = (wave >> 1)*64;
  int dhlo = (2-h > 0) ? (2-h) : 0;
  int dhhi = (H+1-h < 4) ? (H+1-h) : 4;
  int nslab = (dhhi - dhlo + 1) << LN;
  int P = nslab * 5;
  const u16* inN = in + (size_t)n*H*WST*IC;

  auto stageW = [&](int slab_, int dw_, int buf){
    int dh = dhlo + (slab_ >> LN);
    int icb = slab_ & (NICB-1);
    int tap = dh*5 + dw_;
    const u16* wsrc = wp + ((size_t)tap*OC + ocb)*IC + icb*128;
    u16* dst = &sW[buf][wave*4096];
    #pragma unroll
    for (int j = 0; j < 8; ++j){
      int q = (wave*8 + j)*64 + lane;
      int r = q >> 4, cp = q & 15;
      int c = cp ^ (r & 7);
      gll16(wsrc + (size_t)r*IC + c*8, dst + j*512);
    }
  };
  auto stageI = [&](int slab_, int buf){
    int dh = dhlo + (slab_ >> LN);
    int icb = slab_ & (NICB-1);
    int hin = h + dh - 2;
    const u16* src = inN + (size_t)hin*WST*IC + (size_t)icb*128;
    u16* dst = &sIn[buf][wave*4608];
    #pragma unroll
    for (int j = 0; j < 9; ++j){
      int q = (wave*9 + j)*64 + lane;
      int r = q >> 4, cp = q & 15;
      int c = cp ^ (r & 7);
      int col = w0 + r; col = (col < WST) ? col : (WST-1);
      gll16(src + (size_t)col*IC + c*8, dst + j*512);
    }
  };

  f32x4 acc[4][4] = {};
  stageI(0, 0);
  stageW(0, 0, 0);
  int slab = 0, dw = 0;
  for (int p = 0; p < P; ++p){
    {
      int dwn = dw + 1, slabn = slab;
      if (dwn == 5){ dwn = 0; slabn = slab + 1; if (slabn == nslab){ slabn = slab; dwn = dw; } }
      stageW(slabn, dwn, (p+1)&1);
    }
    if (dw == 3){
      int sn = slab + 1; if (sn == nslab) sn = slab;
      stageI(sn, (slab+1)&1);
    }
    if (dw >= 3) asm volatile("s_waitcnt vmcnt(17)" ::: "memory");
    else         asm volatile("s_waitcnt vmcnt(8)"  ::: "memory");
    __builtin_amdgcn_s_barrier();
    __builtin_amdgcn_sched_barrier(0);
    const u16* sWp = sW[p&1];
    const u16* sInp = sIn[slab&1];
    #pragma unroll
    for (int k0i = 0; k0i < 4; ++k0i){
      bf16x8 A[4], B[4];
      #pragma unroll
      for (int j = 0; j < 4; ++j){
        int ar = wo_oc + j*16 + lr;
        A[j] = *(const bf16x8*)&sWp[ar*128 + (((k0i*4 + lgp) ^ (lr & 7)) << 3)];
        int br = wo_w + j*16 + lr + dw;
        B[j] = *(const bf16x8*)&sInp[br*128 + (((k0i*4 + lgp) ^ (br & 7)) << 3)];
      }
      #pragma unroll
      for (int ja = 0; ja < 4; ++ja)
        #pragma unroll
        for (int jb = 0; jb < 4; ++jb)
          acc[ja][jb] = __builtin_amdgcn_mfma_f32_16x16x32_bf16(A[ja], B[jb], acc[ja][jb], 0, 0, 0);
    }
    __builtin_amdgcn_sched_barrier(0);
    __builtin_amdgcn_s_barrier();
    ++dw; if (dw == 5){ dw = 0; ++slab; }
  }
  asm volatile("s_waitcnt vmcnt(0)" ::: "memory");  // drain before endpgm (LDS writes)
  const size_t obase = ((size_t)(n*H + h)*WST + 2)*OC;
  #pragma unroll
  for (int ja = 0; ja < 4; ++ja){
    int oc = ocb + wo_oc + ja*16 + lgp*4;
    float4 bv = *(const float4*)&bias[oc];
    #pragma unroll
    for (int jb = 0; jb < 4; ++jb){
      int wg = w0 + wo_w + jb*16 + lr;
      if (wg < WPAD){
        f32x4 av = acc[ja][jb];
        ushort4 o;
        o.x = f2bf(av[0] + bv.x);
        o.y = f2bf(av[1] + bv.y);
        o.z = f2bf(av[2] + bv.z);
        o.w = f2bf(av[3] + bv.w);
        *(ushort4*)(out + obase + (size_t)wg*OC + oc) = o;
      }
    }
  }
}

// leaky(0.2) + maxpool 3x3 stride(3,1); 4 oc/thread (8B loads); writes full guarded range
__global__ __launch_bounds__(256) void pool1k(const u16* __restrict__ in, u16* __restrict__ out){
  int t = threadIdx.x;
  int wb = blockIdx.x*4 + (t >> 6);
  int oc = (t & 63)*4;
  int ho = blockIdx.y, n = blockIdx.z;
  int wo = wb - 2;
  float m0=0.f,m1=0.f,m2=0.f,m3=0.f;
  if (wo >= 0 && wo < WPAD){
    m0=m1=m2=m3=-1e30f;
    #pragma unroll
    for (int kh = 0; kh < 3; ++kh){
      const u16* row = in + ((size_t)(n*HH + ho*3 + kh)*WST + 2)*OC1 + oc;
      #pragma unroll
      for (int kw = 0; kw < 3; ++kw){
        int wi = wo - 1 + kw;
        if (wi >= 0 && wi < WPAD){
          ushort4 v = *(const ushort4*)(row + (size_t)wi*OC1);
          m0 = fmaxf(m0, bf2f(v.x)); m1 = fmaxf(m1, bf2f(v.y));
          m2 = fmaxf(m2, bf2f(v.z)); m3 = fmaxf(m3, bf2f(v.w));
        }
      }
    }
    m0 = (m0>0.f)?m0:0.2f*m0; m1 = (m1>0.f)?m1:0.2f*m1;
    m2 = (m2>0.f)?m2:0.2f*m2; m3 = (m3>0.f)?m3:0.2f*m3;
  }
  ushort4 o; o.x=f2bf(m0); o.y=f2bf(m1); o.z=f2bf(m2); o.w=f2bf(m3);
  *(ushort4*)(out + ((size_t)(n*16 + ho)*WST + wb)*OC1 + oc) = o;
}

// leaky(0.2) + maxpool 4x5 stride(4,1); 4 oc/thread
__global__ __launch_bounds__(256) void pool2k(const u16* __restrict__ in, u16* __restrict__ out){
  int t = threadIdx.x;
  int wb = blockIdx.x*2 + (t >> 7);
  int oc = (t & 127)*4;
  int ho = blockIdx.y, n = blockIdx.z;
  int wo = wb - 2;
  float m0=0.f,m1=0.f,m2=0.f,m3=0.f;
  if (wo >= 0 && wo < WPAD){
    m0=m1=m2=m3=-1e30f;
    #pragma unroll
    for (int kh = 0; kh < 4; ++kh){
      const u16* row = in + ((size_t)(n*16 + ho*4 + kh)*WST + 2)*OC2 + oc;
      #pragma unroll
      for (int kw = 0; kw < 5; ++kw){
        int wi = wo - 2 + kw;
        if (wi >= 0 && wi < WPAD){
          ushort4 v = *(const ushort4*)(row + (size_t)wi*OC2);
          m0 = fmaxf(m0, bf2f(v.x)); m1 = fmaxf(m1, bf2f(v.y));
          m2 = fmaxf(m2, bf2f(v.z)); m3 = fmaxf(m3, bf2f(v.w));
        }
      }
    }
    m0 = (m0>0.f)?m0:0.2f*m0; m1 = (m1>0.f)?m1:0.2f*m1;
    m2 = (m2>0.f)?m2:0.2f*m2; m3 = (m3>0.f)?m3:0.2f*m3;
  }
  ushort4 o; o.x=f2bf(m0); o.y=f2bf(m1); o.z=f2bf(m2); o.w=f2bf(m3);
  *(ushort4*)(out + ((size_t)(n*4 + ho)*WST + wb)*OC2 + oc) = o;
}

// maxpool 1x200 over one h-row, sampled every 30; partials per h -> xfraw [n][t][4][1024]
__global__ __launch_bounds__(256) void pool3k(const u16* __restrict__ in, float* __restrict__ xfraw){
  int tt = blockIdx.x, hh = blockIdx.y, n = blockIdx.z;
  int oc = threadIdx.x*4;
  float m0=-1e30f,m1=-1e30f,m2=-1e30f,m3=-1e30f;
  const u16* row = in + ((size_t)(n*4 + hh)*WST + 2 + 30*tt)*OC3 + oc;
  for (int p = 0; p < 200; ++p){
    ushort4 v = *(const ushort4*)(row + (size_t)p*OC3);
    m0 = fmaxf(m0, bf2f(v.x)); m1 = fmaxf(m1, bf2f(v.y));
    m2 = fmaxf(m2, bf2f(v.z)); m3 = fmaxf(m3, bf2f(v.w));
  }
  float* dst = xfraw + (((size_t)(n*NT + tt))*4 + hh)*OC3 + oc;
  dst[0]=m0; dst[1]=m1; dst[2]=m2; dst[3]=m3;
}

// combine 4 h-partials, L2 normalize -> xf [row][1024]
__global__ __launch_bounds__(256) void xf_norm(const float* __restrict__ xfraw, float* __restrict__ xf){
  int row = blockIdx.x, t = threadIdx.x;
  const float* src = xfraw + (size_t)row*4096;
  float v[4]; float ss = 0.f;
  #pragma unroll
  for (int j = 0; j < 4; ++j){
    float m = src[t + j*256];
    #pragma unroll
    for (int hh = 1; hh < 4; ++hh) m = fmaxf(m, src[hh*1024 + t + j*256]);
    v[j] = m; ss += m*m;
  }
  #pragma unroll
  for (int m = 1; m < 64; m <<= 1) ss += __shfl_xor(ss, m);
  __shared__ float red[4];
  if ((t & 63) == 0) red[t >> 6] = ss;
  __syncthreads();
  float tot = red[0]+red[1]+red[2]+red[3];
  float inv = 1.f/fmaxf(sqrtf(tot), 1e-12f);
  float* dst = xf + (size_t)row*OC3;
  #pragma unroll
  for (int j = 0; j < 4; ++j) dst[t + j*256] = v[j]*inv;
}

__global__ __launch_bounds__(256) void final_mlp(const float* __restrict__ vlad, const float* __restrict__ xf,
    const float* __restrict__ W, const float* __restrict__ b, float* __restrict__ out){
  __shared__ float feat[9216];
  __shared__ float red[4];
  int row = blockIdx.x, t = threadIdx.x;
  {
    const float4* v = (const float4*)(vlad + (size_t)row*8192);
    float4* f4 = (float4*)feat;
    for (int i = t; i < 2048; i += 256) f4[i] = v[i];
    const float4* xv = (const float4*)(xf + (size_t)row*1024);
    if (t < 256) f4[2048 + t] = xv[t];
  }
  __syncthreads();
  const float* wr = W + (size_t)t*9216;
  float acc = b[t];
  for (int i = 0; i < 9216; i += 4){
    float4 wv = *(const float4*)&wr[i];
    acc += feat[i]*wv.x + feat[i+1]*wv.y + feat[i+2]*wv.z + feat[i+3]*wv.w;
  }
  float ss = acc*acc;
  #pragma unroll
  for (int m = 1; m < 64; m <<= 1) ss += __shfl_xor(ss, m);
  if ((t & 63) == 0) red[t >> 6] = ss;
  __syncthreads();
  float tot = red[0]+red[1]+red[2]+red[3];
  float inv = 1.f/fmaxf(sqrtf(tot), 1e-12f);
  out[(size_t)row*256 + t] = acc*inv;
}

// ---------------- launch ----------------
extern "C" void kernel_launch(void* const* d_in, const int* in_sizes, int n_in,
                              void* d_out, int out_size, void* d_ws, size_t ws_size,
                              hipStream_t stream){
  const float* x       = (const float*)d_in[0];
  const float* centers = (const float*)d_in[1];
  const float* conv_w  = (const float*)d_in[2];
  const float* conv_b  = (const float*)d_in[3];
  const float* w1      = (const float*)d_in[4];
  const float* b1      = (const float*)d_in[5];
  const float* w2      = (const float*)d_in[6];
  const float* b2      = (const float*)d_in[7];
  const float* w3      = (const float*)d_in[8];
  const float* b3      = (const float*)d_in[9];
  const float* mlp_w   = (const float*)d_in[10];
  const float* mlp_b   = (const float*)d_in[11];
  float* out = (float*)d_out;
  char* ws = (char*)d_ws;
  const size_t MB = 1ull << 20;
  if (ws_size < 248*MB) return;

  // persistent small buffers
  float* vlad  = (float*)(ws + 0);        // 3.75 MiB
  float* xf    = (float*)(ws + 4*MB);     // 0.47 MiB
  float* xfraw = (float*)(ws + 5*MB);     // 1.97 MiB (5..7 MB)
  char*  AR    = ws + 7*MB;               // arena (241 MiB), phase-reused
  // VLAD phase
  float* xt = (float*)(AR + 0);           // 84.4 MiB
  float* a  = (float*)(AR + 85*MB);       // 42.2 MiB (dead after vlad_xa)
  float* cs = (float*)(AR + 85*MB);       // 8.4 MiB (over a, written by vlad_scan)
  float* ya = (float*)(AR + 128*MB);      // 112.6 MiB
  // conv phase (after vlad_win2; regions recycled, stream-ordered)
  u16* xpb = (u16*)(AR + 0);              // 54.4 MiB (over xt)
  u16* wp1 = (u16*)(AR + 55*MB);          // 1.6 MiB
  u16* wp2 = (u16*)(AR + 57*MB);          // 6.25 MiB
  u16* wp3 = (u16*)(AR + 64*MB);          // 25 MiB
  u16* h1  = (u16*)(AR + 89*MB);          // 108.75 MiB (over cs/ya)
  u16* p1  = (u16*)(AR + 0);              // 36.25 MiB (over xpb, dead after conv1)
  u16* h2  = (u16*)(AR + 89*MB);          // 72.5 MiB (over h1, dead after pool1)
  u16* p2  = (u16*)(AR + 163*MB);         // 18.1 MiB (past h2)
  u16* h3  = (u16*)(AR + 0);              // 36.25 MiB (over p1, dead after conv2)

  // ---- VLAD (fp32) ----
  transpose_xt<<<dim3(29,192,NB), 256, 0, stream>>>(x, xt);
  vlad_softmax<<<dim3(4,HH,NB), 256, 0, stream>>>(x, conv_w, conv_b, a);
  vlad_xa<<<dim3(WW,NB), 256, 0, stream>>>(xt, a, centers, ya);
  vlad_scan<<<dim3(KC,NB), 128, 0, stream>>>(ya, cs);
  vlad_win2<<<dim3(KC,NT,NB), 128, 0, stream>>>(cs, vlad);
  vlad_gnorm<<<dim3(NB*NT), 256, 0, stream>>>(vlad);

  // ---- conv tower (bf16 MFMA) ----
  pack_w<<<dim3(3200),  256, 0, stream>>>(w1, wp1, OC1, DIM);
  pack_w<<<dim3(12800), 256, 0, stream>>>(w2, wp2, OC2, OC1);
  pack_w<<<dim3(51200), 256, 0, stream>>>(w3, wp3, OC3, OC2);
  build_xpb<<<dim3(37,HH,NB), 256, 0, stream>>>(x, xpb);
  conv5x5<128,256,48><<<dim3(9, OC1/128, NB*HH), 256, 0, stream>>>(xpb, wp1, b1, h1);
  pool1k<<<dim3(WST/4,16,NB), 256, 0, stream>>>(h1, p1);
  conv5x5<256,512,16><<<dim3(9, OC2/128, NB*16), 256, 0, stream>>>(p1, wp2, b2, h2);
  pool2k<<<dim3(WST/2,4,NB), 256, 0, stream>>>(h2, p2);
  conv5x5<512,1024,4><<<dim3(9, OC3/128, NB*4), 256, 0, stream>>>(p2, wp3, b3, h3);
  pool3k<<<dim3(NT,4,NB), 256, 0, stream>>>(h3, xfraw);
  xf_norm<<<dim3(NB*NT), 256, 0, stream>>>(xfraw, xf);

  // ---- head ----
  final_mlp<<<dim3(NB*NT), 256, 0, stream>>>(vlad, xf, mlp_w, mlp_b, out);
}